// Round 1
// 692.607 us; speedup vs baseline: 1.3486x; 1.3486x over previous
//
#include <hip/hip_runtime.h>
#include <hip/hip_bf16.h>

typedef __hip_bfloat16 bf16;
typedef __bf16 bf16v8 __attribute__((ext_vector_type(8)));
typedef float f32x4 __attribute__((ext_vector_type(4)));

#define BB    128
#define DIM   384
#define NTOK  256
#define NH    8
#define KD    32
#define DHEAD 128
#define DH    1024
#define SCALE 0.17677669529663687f

// sanitize boundary reads: NaN->0, clamp huge
static __device__ __forceinline__ float sf(float x) {
  return (x == x) ? fminf(fmaxf(x, -1e4f), 1e4f) : 0.f;
}

// ---------------- K-1a: fp32 weights -> bf16 copies in ws ----------------
__global__ __launch_bounds__(256) void k_convert(const float* __restrict__ qw,
    const float* __restrict__ kw, const float* __restrict__ vw,
    const float* __restrict__ pw, bf16* __restrict__ dst) {
  int i = blockIdx.x * 256 + threadIdx.x;
  float v;
  if (i < 98304)       v = qw[i];
  else if (i < 196608) v = kw[i - 98304];
  else if (i < 589824) v = vw[i - 196608];
  else                 v = pw[i - 589824];
  dst[i] = __float2bfloat16(sf(v));
}

// ---------------- K-1b: bias_full[h][n][m] = ab[h][idxs[n][m]] (batch-independent) ----------------
__global__ __launch_bounds__(256) void k_bias(const float* __restrict__ ab,
    const int* __restrict__ idxs, int n_off, float* __restrict__ bias_full) {
  int i = blockIdx.x * 256 + threadIdx.x;   // 8*65536
  int h = i >> 16, nm = i & 65535;
  bias_full[i] = sf(ab[h * n_off + idxs[nm]]);
}

// ---------------- K0: x fp32 [cb,384,256] -> xT bf16 [cb,256,384] ----------------
__global__ __launch_bounds__(256) void k_transpose_x(const float* __restrict__ x,
                                                     bf16* __restrict__ xT) {
  __shared__ bf16 tile[32][33];
  int b = blockIdx.z;
  int c0 = blockIdx.x * 32;
  int n0 = blockIdx.y * 32;
  int t = threadIdx.x;
  int tn = t & 31, tc = t >> 5;
#pragma unroll
  for (int p = 0; p < 4; ++p)
    tile[tc + p * 8][tn] =
        __float2bfloat16(sf(x[((size_t)b * DIM + c0 + tc + p * 8) * NTOK + n0 + tn]));
  __syncthreads();
  int wc = t & 31, wn = t >> 5;
#pragma unroll
  for (int p = 0; p < 4; ++p)
    xT[((size_t)b * NTOK + n0 + wn + p * 8) * DIM + c0 + wc] = tile[wc][wn + p * 8];
}

// ---------------- K1: QKV GEMM (chunk-local; XCD-swizzled grid cb*24) ----------------
__global__ __launch_bounds__(256, 4) void k_qkv(const bf16* __restrict__ xT,
    const bf16* __restrict__ q_w, const float* __restrict__ q_b,
    const bf16* __restrict__ k_w, const float* __restrict__ k_b,
    const bf16* __restrict__ v_w, const float* __restrict__ v_b,
    bf16* __restrict__ qT, bf16* __restrict__ kT, bf16* __restrict__ v4,
    int nb) {
  int id = blockIdx.x;
  int b, mt;
  if ((nb & 7) == 0) {
    int per = nb >> 3;
    int xcd = id & 7, slot = id >> 3;
    b = xcd * per + (slot % per);
    mt = slot / per;            // [0,24)
  } else { b = id / 24; mt = id % 24; }
  int m0 = mt * 64;
  int wave = threadIdx.x >> 6;
  int lane = threadIdx.x & 63;
  int qd = lane >> 4, li = lane & 15;
  int n0 = wave * 64;
  f32x4 acc[4][4];
#pragma unroll
  for (int r = 0; r < 4; ++r)
#pragma unroll
    for (int f = 0; f < 4; ++f) acc[r][f] = (f32x4){0.f, 0.f, 0.f, 0.f};
  for (int k0 = 0; k0 < DIM; k0 += 32) {
    bf16v8 Af[4], Bf[4];
#pragma unroll
    for (int r = 0; r < 4; ++r) {
      int o = m0 + r * 16 + li;
      const bf16* wp = (o < 256) ? (q_w + o * DIM)
                     : (o < 512) ? (k_w + (o - 256) * DIM)
                                 : (v_w + (o - 512) * DIM);
      Af[r] = *(const bf16v8*)(wp + k0 + qd * 8);
    }
#pragma unroll
    for (int f = 0; f < 4; ++f)
      Bf[f] = *(const bf16v8*)(xT + ((size_t)b * NTOK + n0 + f * 16 + li) * DIM + k0 + qd * 8);
#pragma unroll
    for (int r = 0; r < 4; ++r)
#pragma unroll
      for (int f = 0; f < 4; ++f)
        acc[r][f] = __builtin_amdgcn_mfma_f32_16x16x32_bf16(Af[r], Bf[f], acc[r][f], 0, 0, 0);
  }
#pragma unroll
  for (int r = 0; r < 4; ++r) {
#pragma unroll
    for (int f = 0; f < 4; ++f) {
      int n = n0 + f * 16 + li;
#pragma unroll
      for (int rr = 0; rr < 4; ++rr) {
        int o = m0 + r * 16 + qd * 4 + rr;
        float val = acc[r][f][rr];
        if (o < 256) {
          int h = o >> 5, kd = o & 31;
          val += sf(q_b[o]);
          qT[(((size_t)b * NH + h) * NTOK + n) * KD + kd] = __float2bfloat16(val);
        } else if (o < 512) {
          int o2 = o - 256;
          int h = o2 >> 5, kd = o2 & 31;
          val += sf(k_b[o2]);
          kT[(((size_t)b * NH + h) * NTOK + n) * KD + kd] = __float2bfloat16(val);
        } else {
          int ch = o - 512;
          val += sf(v_b[ch]);
          v4[((size_t)b * DH + ch) * NTOK + n] = __float2bfloat16(val);
        }
      }
    }
  }
}

// ---------------- K2: scores + TH1 + softmax + TH2 -> P blocked [b][g][nt16][mb8][nl16][m32] ----------------
__global__ __launch_bounds__(512, 2) void k_scores(const bf16* __restrict__ qT,
    const bf16* __restrict__ kT, const float* __restrict__ bias_full,
    const float* __restrict__ th1_w, const float* __restrict__ th1_b,
    const float* __restrict__ th2_w, const float* __restrict__ th2_b,
    bf16* __restrict__ P, int nb) {
  __shared__ bf16 stage[4][8][16][32];   // 32 KB: [g2 round][wave][nl][m]
  __shared__ float s_th1[64], s_th2[64], s_t1b[8], s_t2b[8];
  __shared__ float s_part[8][8][16];
  __shared__ float s_invl[8][16];
  int t = threadIdx.x;
  if (t < 64) { s_th1[t] = sf(th1_w[t]); s_th2[t] = sf(th2_w[t]); }
  if (t >= 64 && t < 72) s_t1b[t - 64] = sf(th1_b[t - 64]);
  if (t >= 72 && t < 80) s_t2b[t - 72] = sf(th2_b[t - 72]);
  int id = blockIdx.x;
  int b, nt;
  if ((nb & 7) == 0) {
    int per = nb >> 3;
    int xcd = id & 7, slot = id >> 3;
    b = xcd * per + (slot % per);
    nt = slot / per;            // [0,16)
  } else { b = id >> 4; nt = id & 15; }
  int n0 = nt * 16;
  int wave = t >> 6, lane = t & 63, qd = lane >> 4, li = lane & 15;
  int ms = wave * 32;

  // ---- QK^T: S[h][mt][r] at (n = n0+qd*4+r, m = ms+mt*16+li) ----
  f32x4 S[8][2];
#pragma unroll
  for (int h = 0; h < 8; ++h) {
    bf16v8 Af = *(const bf16v8*)(qT + (((size_t)b * NH + h) * NTOK + n0 + li) * KD + qd * 8);
#pragma unroll
    for (int mt = 0; mt < 2; ++mt) {
      bf16v8 Bf = *(const bf16v8*)(kT + (((size_t)b * NH + h) * NTOK + ms + mt * 16 + li) * KD + qd * 8);
      f32x4 c = {0.f, 0.f, 0.f, 0.f};
      S[h][mt] = __builtin_amdgcn_mfma_f32_16x16x32_bf16(Af, Bf, c, 0, 0, 0);
    }
  }
  // bias add: coalesced independent loads from bias_full
#pragma unroll
  for (int h = 0; h < 8; ++h)
#pragma unroll
    for (int mt = 0; mt < 2; ++mt)
#pragma unroll
      for (int r = 0; r < 4; ++r)
        S[h][mt][r] = S[h][mt][r] * SCALE +
            bias_full[(size_t)(h * NTOK + n0 + qd * 4 + r) * NTOK + ms + mt * 16 + li];
  __syncthreads();   // th weights staged

  // ---- TH1 + exp (no max-sub; clamp firewall) + row sums ----
  float psum[8][4];
#pragma unroll
  for (int g = 0; g < 8; ++g)
#pragma unroll
    for (int r = 0; r < 4; ++r) psum[g][r] = 0.f;
#pragma unroll
  for (int mt = 0; mt < 2; ++mt)
#pragma unroll
    for (int r = 0; r < 4; ++r) {
      float e[8];
#pragma unroll
      for (int g = 0; g < 8; ++g) {
        float a = s_t1b[g];
#pragma unroll
        for (int h = 0; h < 8; ++h) a += s_th1[g * 8 + h] * S[h][mt][r];
        e[g] = __expf(fminf(a, 30.0f));
        psum[g][r] += e[g];
      }
#pragma unroll
      for (int g = 0; g < 8; ++g) S[g][mt][r] = e[g];
    }
#pragma unroll
  for (int g = 0; g < 8; ++g)
#pragma unroll
    for (int r = 0; r < 4; ++r) {
      float v = psum[g][r];
      v += __shfl_xor(v, 1, 64);
      v += __shfl_xor(v, 2, 64);
      v += __shfl_xor(v, 4, 64);
      v += __shfl_xor(v, 8, 64);
      psum[g][r] = v;
    }
  if (li == 0) {
#pragma unroll
    for (int g = 0; g < 8; ++g)
#pragma unroll
      for (int r = 0; r < 4; ++r) s_part[wave][g][qd * 4 + r] = psum[g][r];
  }
  __syncthreads();
  if (t < 128) {
    int g = t >> 4, n = t & 15;
    float ssum = 0.f;
#pragma unroll
    for (int w2 = 0; w2 < 8; ++w2) ssum += s_part[w2][g][n];
    s_invl[g][n] = 1.0f / ssum;
  }
  __syncthreads();
#pragma unroll
  for (int g = 0; g < 8; ++g)
#pragma unroll
    for (int mt = 0; mt < 2; ++mt)
#pragma unroll
      for (int r = 0; r < 4; ++r)
        S[g][mt][r] *= s_invl[g][qd * 4 + r];

  // ---- TH2 + blocked-coalesced P store via LDS restage (2 rounds of 4 g2) ----
  size_t pb = (size_t)b * NH * 65536 + (size_t)nt * 4096 + wave * 512 + lane * 8;
#pragma unroll
  for (int gr = 0; gr < 2; ++gr) {
#pragma unroll
    for (int g2i = 0; g2i < 4; ++g2i) {
      int g2 = gr * 4 + g2i;
#pragma unroll
      for (int mt = 0; mt < 2; ++mt)
#pragma unroll
        for (int r = 0; r < 4; ++r) {
          float a = s_t2b[g2];
#pragma unroll
          for (int g = 0; g < 8; ++g) a += s_th2[g2 * 8 + g] * S[g][mt][r];
          stage[g2i][wave][qd * 4 + r][mt * 16 + li] = __float2bfloat16(a);
        }
    }
    __syncthreads();
#pragma unroll
    for (int g2i = 0; g2i < 4; ++g2i) {
      int g2 = gr * 4 + g2i;
      bf16v8 vv = *(const bf16v8*)&stage[g2i][wave][lane >> 2][(lane & 3) * 8];
      *(bf16v8*)(P + pb + (size_t)g2 * 65536) = vv;
    }
    __syncthreads();
  }
}

// ---------------- K3: O = P@V + dwconv + relu -> act[b,n,ch] ----------------
// NEW STRUCTURE: block = (chunk-local b, head h); 8 waves x (32n x 128d) = full 256 tokens.
// V head-slab (64 KB) staged ONCE into XOR-swizzled LDS; dwconv reads LDS (was 288
// scalar global loads/thread = the latency bottleneck); dw weights staged in LDS;
// P fragments prefetched into regs BEFORE the staging barrier (latency overlap).
static __device__ __forceinline__ int vswz(int ch, int tok) {
  // XOR 16B-granule index (tok bits 3..5) with ch&7: spreads the stride-512B
  // ds_read_b128 column reads evenly over all 32 banks (rows are 512 B = bank-aligned).
  return tok ^ ((ch & 7) << 3);
}

__global__ __launch_bounds__(512, 1) void k_pv(const bf16* __restrict__ P,
    const bf16* __restrict__ v4,
    const float* __restrict__ vl_w, const float* __restrict__ vl_b,
    bf16* __restrict__ act, int nb) {
  __shared__ bf16 v_s[128][256];     // 64 KB, bank-swizzled via vswz()
  __shared__ bf16 act_s[256][136];   // 68 KB (+8 pad)
  __shared__ float wv_s[1152];       // dw weights for this head: 4.5 KB
  __shared__ float vb_s[128];
  int id = blockIdx.x;
  int b, h;
  if ((nb & 7) == 0) {
    int per = nb >> 3;
    int xcd = id & 7, slot = id >> 3;
    b = xcd * per + (slot % per);
    h = slot / per;            // [0,8)
  } else { b = id >> 3; h = id & 7; }
  int t = threadIdx.x;
  int wave = t >> 6, lane = t & 63;
  int qd = lane >> 4, li = lane & 15;
  int nw = wave * 32;                // 32 tokens per wave
  int nwt = wave * 2;                // n-tile base
  const bf16* Pb = P + ((size_t)b * NH + h) * 65536;
  const bf16* Vb = v4 + ((size_t)b * DH + h * DHEAD) * NTOK;

  // --- prefetch ALL P fragments (latency hides under V staging; drained by barrier) ---
  bf16v8 Af[4][2][2];
#pragma unroll
  for (int mi = 0; mi < 4; ++mi)
#pragma unroll
    for (int s = 0; s < 2; ++s)
#pragma unroll
      for (int r = 0; r < 2; ++r)
        Af[mi][s][r] = *(const bf16v8*)(Pb + (size_t)(nwt + r) * 4096 +
                                        (mi * 2 + s) * 512 + li * 32 + qd * 8);

  // --- stage V slab (coalesced 16B, swizzled LDS dest) + dw weights ---
#pragma unroll
  for (int p = 0; p < 8; ++p) {
    int idx = p * 512 + t;             // 16-B granule id, 4096 total
    int ch = idx >> 5, tok = (idx & 31) * 8;
    *(bf16v8*)&v_s[ch][vswz(ch, tok)] = *(const bf16v8*)(Vb + (size_t)ch * NTOK + tok);
  }
  for (int i = t; i < 1152; i += 512) wv_s[i] = sf(vl_w[(size_t)h * DHEAD * 9 + i]);
  if (t < 128) vb_s[t] = sf(vl_b[h * DHEAD + t]);
  __syncthreads();

  // --- PV GEMM: B operand from swizzled LDS ---
  f32x4 acc[2][8];
#pragma unroll
  for (int r = 0; r < 2; ++r)
#pragma unroll
    for (int f = 0; f < 8; ++f) acc[r][f] = (f32x4){0.f, 0.f, 0.f, 0.f};
#pragma unroll
  for (int mi = 0; mi < 4; ++mi) {
    int m0 = mi * 64;
#pragma unroll
    for (int s = 0; s < 2; ++s) {
      bf16v8 Bf[8];
#pragma unroll
      for (int f = 0; f < 8; ++f) {
        int ch = f * 16 + li;
        Bf[f] = *(const bf16v8*)&v_s[ch][vswz(ch, m0 + s * 32 + qd * 8)];
      }
#pragma unroll
      for (int f = 0; f < 8; ++f)
#pragma unroll
        for (int r = 0; r < 2; ++r)
          acc[r][f] = __builtin_amdgcn_mfma_f32_16x16x32_bf16(Af[mi][s][r], Bf[f], acc[r][f], 0, 0, 0);
    }
  }

  // --- epilogue: dwconv 3x3 entirely from LDS + relu -> act_s ---
#pragma unroll
  for (int f = 0; f < 8; ++f) {
    int chl = f * 16 + li;
    float wv[9];
#pragma unroll
    for (int j = 0; j < 9; ++j) wv[j] = wv_s[chl * 9 + j];
    float vb = vb_s[chl];
#pragma unroll
    for (int r = 0; r < 2; ++r) {
      int nbase = nw + r * 16;          // y = nbase/16, x = qd*4..qd*4+3
      int y = nbase >> 4;
      float vv[3][6];
#pragma unroll
      for (int yy = 0; yy < 3; ++yy) {
        int y3 = y - 1 + yy;
#pragma unroll
        for (int c = 0; c < 6; ++c) {
          int x = qd * 4 - 1 + c;
          vv[yy][c] = (y3 >= 0 && y3 < 16 && x >= 0 && x < 16)
                      ? __bfloat162float(v_s[chl][vswz(chl, y3 * 16 + x)]) : 0.f;
        }
      }
#pragma unroll
      for (int rr = 0; rr < 4; ++rr) {
        float s = vb;
#pragma unroll
        for (int yy = 0; yy < 3; ++yy)
#pragma unroll
          for (int j = 0; j < 3; ++j)
            s += vv[yy][rr + j] * wv[yy * 3 + j];
        float v = fmaxf(acc[r][f][rr] + s, 0.f);
        act_s[nbase + qd * 4 + rr][chl] = __float2bfloat16(v);
      }
    }
  }
  __syncthreads();
  // coalesced act write: rows of 256 B (128 ch x bf16)
  for (int it = t; it < 4096; it += 512) {
    int row = it >> 4, seg = it & 15;
    bf16v8 vv = *(const bf16v8*)&act_s[row][seg * 8];
    *(bf16v8*)(act + ((size_t)b * NTOK + row) * DH + h * DHEAD + seg * 8) = vv;
  }
}

// ---------------- K4: proj GEMM out[b,dim,tok] = wp @ act^T + proj_b ----------------
__global__ __launch_bounds__(256, 4) void k_proj(const bf16* __restrict__ act,
    const bf16* __restrict__ proj_w, const float* __restrict__ proj_b,
    int b_base, int nb, float* __restrict__ out) {
  int id = blockIdx.x;
  int b, mt;
  if ((nb & 7) == 0) {
    int per = nb >> 3;
    int xcd = id & 7, slot = id >> 3;
    b = xcd * per + (slot % per);
    mt = slot / per;            // [0,6)
  } else { b = id / 6; mt = id % 6; }
  int m0 = mt * 64;
  int bg = b_base + b;
  int wave = threadIdx.x >> 6, lane = threadIdx.x & 63;
  int qd = lane >> 4, li = lane & 15;
  int n0 = wave * 64;
  f32x4 acc[4][4];
#pragma unroll
  for (int r = 0; r < 4; ++r)
#pragma unroll
    for (int f = 0; f < 4; ++f) acc[r][f] = (f32x4){0.f, 0.f, 0.f, 0.f};
  for (int k0 = 0; k0 < DH; k0 += 32) {
    bf16v8 Af[4], Bf[4];
#pragma unroll
    for (int r = 0; r < 4; ++r)
      Af[r] = *(const bf16v8*)(proj_w + (size_t)(m0 + r * 16 + li) * DH + k0 + qd * 8);
#pragma unroll
    for (int f = 0; f < 4; ++f)
      Bf[f] = *(const bf16v8*)(act + ((size_t)b * NTOK + n0 + f * 16 + li) * DH + k0 + qd * 8);
#pragma unroll
    for (int r = 0; r < 4; ++r)
#pragma unroll
      for (int f = 0; f < 4; ++f)
        acc[r][f] = __builtin_amdgcn_mfma_f32_16x16x32_bf16(Af[r], Bf[f], acc[r][f], 0, 0, 0);
  }
#pragma unroll
  for (int r = 0; r < 4; ++r)
#pragma unroll
    for (int f = 0; f < 4; ++f) {
      int n = n0 + f * 16 + li;
#pragma unroll
      for (int rr = 0; rr < 4; ++rr) {
        int dim = m0 + r * 16 + qd * 4 + rr;
        out[((size_t)bg * DIM + dim) * NTOK + n] = acc[r][f][rr] + sf(proj_b[dim]);
      }
    }
}

extern "C" void kernel_launch(void* const* d_in, const int* in_sizes, int n_in,
                              void* d_out, int out_size, void* d_ws, size_t ws_size,
                              hipStream_t stream) {
  const float* x      = (const float*)d_in[0];
  const float* q_w    = (const float*)d_in[1];
  const float* q_b    = (const float*)d_in[2];
  const float* k_w    = (const float*)d_in[3];
  const float* k_b    = (const float*)d_in[4];
  const float* v_w    = (const float*)d_in[5];
  const float* v_b    = (const float*)d_in[6];
  const float* vl_w   = (const float*)d_in[7];
  const float* vl_b   = (const float*)d_in[8];
  const float* th1_w  = (const float*)d_in[9];
  const float* th1_b  = (const float*)d_in[10];
  const float* th2_w  = (const float*)d_in[11];
  const float* th2_b  = (const float*)d_in[12];
  const float* proj_w = (const float*)d_in[13];
  const float* proj_b = (const float*)d_in[14];
  const float* attn_b = (const float*)d_in[15];
  const int*   idxs   = (const int*)d_in[16];
  int n_off = in_sizes[15] / NH;
  float* out = (float*)d_out;

  const size_t WQ = 98304, WK = 98304, WV = 393216, WP = 393216;
  const size_t WTOT = WQ + WK + WV + WP;                       // 983040 elem
  const size_t BFULL = (size_t)NH * NTOK * NTOK;               // 524288 f32
  const size_t PB_XT = (size_t)NTOK * DIM;                     // 98304
  const size_t PB_QK = (size_t)NH * NTOK * KD;                 // 65536
  const size_t PB_V  = (size_t)DH * NTOK;                      // 262144
  const size_t PB_AC = (size_t)NTOK * DH;                      // 262144
  const size_t PB_P  = (size_t)NH * NTOK * NTOK;               // 524288
  const size_t perb  = (PB_XT + 2 * PB_QK + PB_V + PB_AC + PB_P) * 2;  // 2555904 B
  const size_t fixed = WTOT * 2 + BFULL * 4;

  char* w = (char*)d_ws;
  bf16* wcvt = (bf16*)w;  w += WTOT * 2;
  bf16* wq = wcvt;
  bf16* wk = wcvt + WQ;
  bf16* wv = wcvt + WQ + WK;
  bf16* wp = wcvt + WQ + WK + WV;
  float* bias_full = (float*)w;  w += BFULL * 4;

  size_t rem = (ws_size > fixed) ? (ws_size - fixed) : 0;
  int CH = (int)(rem / perb);
  if (CH > BB) CH = BB;
  if (CH >= 8) CH &= ~7;      // multiple of 8 -> XCD swizzle active
  if (CH < 1) CH = 1;

  bf16* xT  = (bf16*)w;  w += (size_t)CH * PB_XT * 2;
  bf16* qT  = (bf16*)w;  w += (size_t)CH * PB_QK * 2;
  bf16* kT  = (bf16*)w;  w += (size_t)CH * PB_QK * 2;
  bf16* v4  = (bf16*)w;  w += (size_t)CH * PB_V * 2;
  bf16* act = (bf16*)w;  w += (size_t)CH * PB_AC * 2;
  bf16* P   = (bf16*)w;  w += (size_t)CH * PB_P * 2;

  k_convert<<<(int)(WTOT / 256), 256, 0, stream>>>(q_w, k_w, v_w, proj_w, wcvt);
  k_bias<<<(int)(BFULL / 256), 256, 0, stream>>>(attn_b, idxs, n_off, bias_full);

  for (int c0 = 0; c0 < BB; c0 += CH) {
    int cb = (BB - c0 < CH) ? (BB - c0) : CH;
    k_transpose_x<<<dim3(12, 8, cb), 256, 0, stream>>>(x + (size_t)c0 * DIM * NTOK, xT);
    k_qkv<<<cb * 24, 256, 0, stream>>>(xT, wq, q_b, wk, k_b, wv, v_b, qT, kT, v4, cb);
    k_scores<<<cb * 16, 512, 0, stream>>>(qT, kT, bias_full,
                                          th1_w, th1_b, th2_w, th2_b, P, cb);
    k_pv<<<cb * 8, 512, 0, stream>>>(P, v4, vl_w, vl_b, act, cb);
    k_proj<<<cb * 6, 256, 0, stream>>>(act, wp, proj_b, c0, cb, out);
  }
}

// Round 2
// 539.556 us; speedup vs baseline: 1.7311x; 1.2837x over previous
//
#include <hip/hip_runtime.h>
#include <hip/hip_bf16.h>

typedef __hip_bfloat16 bf16;
typedef __bf16 bf16v8 __attribute__((ext_vector_type(8)));
typedef float f32x4 __attribute__((ext_vector_type(4)));

#define BB    128
#define DIM   384
#define NTOK  256
#define NH    8
#define KD    32
#define DHEAD 128
#define DH    1024
#define SCALE 0.17677669529663687f

// sanitize boundary reads: NaN->0, clamp huge
static __device__ __forceinline__ float sf(float x) {
  return (x == x) ? fminf(fmaxf(x, -1e4f), 1e4f) : 0.f;
}

#define GLOAD_LDS16(gsrc, ldst)                                                \
  __builtin_amdgcn_global_load_lds(                                            \
      (const __attribute__((address_space(1))) void*)(gsrc),                   \
      (__attribute__((address_space(3))) void*)(ldst), 16, 0, 0)

// ---------------- K-1a: fp32 weights -> bf16 copies in ws ----------------
__global__ __launch_bounds__(256) void k_convert(const float* __restrict__ qw,
    const float* __restrict__ kw, const float* __restrict__ vw,
    const float* __restrict__ pw, bf16* __restrict__ dst) {
  int i = blockIdx.x * 256 + threadIdx.x;
  float v;
  if (i < 98304)       v = qw[i];
  else if (i < 196608) v = kw[i - 98304];
  else if (i < 589824) v = vw[i - 196608];
  else                 v = pw[i - 589824];
  dst[i] = __float2bfloat16(sf(v));
}

// ---------------- K-1b: bias_full[h][n][m] = ab[h][idxs[n][m]] (batch-independent) ----------------
__global__ __launch_bounds__(256) void k_bias(const float* __restrict__ ab,
    const int* __restrict__ idxs, int n_off, float* __restrict__ bias_full) {
  int i = blockIdx.x * 256 + threadIdx.x;   // 8*65536
  int h = i >> 16, nm = i & 65535;
  bias_full[i] = sf(ab[h * n_off + idxs[nm]]);
}

// ---------------- K0: x fp32 [cb,384,256] -> xT bf16 [cb,256,384] ----------------
__global__ __launch_bounds__(256) void k_transpose_x(const float* __restrict__ x,
                                                     bf16* __restrict__ xT) {
  __shared__ bf16 tile[32][33];
  int b = blockIdx.z;
  int c0 = blockIdx.x * 32;
  int n0 = blockIdx.y * 32;
  int t = threadIdx.x;
  int tn = t & 31, tc = t >> 5;
#pragma unroll
  for (int p = 0; p < 4; ++p)
    tile[tc + p * 8][tn] =
        __float2bfloat16(sf(x[((size_t)b * DIM + c0 + tc + p * 8) * NTOK + n0 + tn]));
  __syncthreads();
  int wc = t & 31, wn = t >> 5;
#pragma unroll
  for (int p = 0; p < 4; ++p)
    xT[((size_t)b * NTOK + n0 + wn + p * 8) * DIM + c0 + wc] = tile[wc][wn + p * 8];
}

// ---------------- K1: QKV GEMM, LDS-staged m97-style ----------------
// C[1536 x 256] = W[1536 x 384] @ xT[b]^T.  W = concat(q_w,k_w,v_w) = wcvt slab.
// Block: 128m x 128n (12 m-tiles x 2 n-tiles = 24/batch), 4 waves 2x2, BK=64.
// Staging: global_load_lds w=16, linear LDS dest + XOR-preswizzled SOURCE
// (slot^=row&7 on 16B granules of the 128B row) -> ds_read_b128 conflict-free.
__global__ __launch_bounds__(256, 3) void k_qkv(const bf16* __restrict__ xT,
    const bf16* __restrict__ W, const float* __restrict__ q_b,
    const float* __restrict__ k_b, const float* __restrict__ v_b,
    bf16* __restrict__ qT, bf16* __restrict__ kT, bf16* __restrict__ v4,
    int nb) {
  __shared__ __align__(16) char smem[34816];   // stage A16K+B16K | v-epilogue tile 128x136 bf16
  bf16* sA = (bf16*)smem;                      // [128][64]
  bf16* sB = (bf16*)(smem + 16384);            // [128][64]
  bf16* actt = (bf16*)smem;                    // [128][136]

  int id = blockIdx.x;
  int b, tile;
  if ((nb & 7) == 0) {
    int per = nb >> 3;
    int xcd = id & 7, slot = id >> 3;
    b = xcd * per + (slot % per);
    tile = slot / per;          // [0,24)
  } else { b = id / 24; tile = id % 24; }
  int mt = tile >> 1, nt = tile & 1;
  int m0 = mt * 128, n0b = nt * 128;
  int t = threadIdx.x;
  int wave = t >> 6, lane = t & 63;
  int wm = wave >> 1, wn = wave & 1;
  int qd = lane >> 4, li = lane & 15;
  const bf16* xTb = xT + ((size_t)b * NTOK + n0b) * DIM;

  f32x4 acc[4][4];
#pragma unroll
  for (int r = 0; r < 4; ++r)
#pragma unroll
    for (int f = 0; f < 4; ++f) acc[r][f] = (f32x4){0.f, 0.f, 0.f, 0.f};

  for (int ks = 0; ks < 6; ++ks) {
    int k0 = ks * 64;
    __syncthreads();            // prev compute done -> safe to overwrite LDS
#pragma unroll
    for (int i = 0; i < 8; ++i) {
      int g = wave * 512 + i * 64 + lane;      // [0,2048) granules; <1024 -> A
      int gg = g & 1023;
      int row = gg >> 3, slot = gg & 7;
      int col = ((slot ^ (row & 7)) << 3) + k0;
      const bf16* src = (g < 1024)
          ? (W + (size_t)(m0 + row) * DIM + col)
          : (xTb + (size_t)row * DIM + col);
      GLOAD_LDS16(src, smem + (size_t)(wave * 512 + i * 64) * 16);
    }
    __syncthreads();            // staging drained (vmcnt(0) at barrier)
#pragma unroll
    for (int s = 0; s < 2; ++s) {
      bf16v8 Afr[4], Bfr[4];
#pragma unroll
      for (int r = 0; r < 4; ++r) {
        int row = wm * 64 + r * 16 + li;
        Afr[r] = *(const bf16v8*)(sA + row * 64 + (((s * 4 + qd) ^ (row & 7)) << 3));
      }
#pragma unroll
      for (int f = 0; f < 4; ++f) {
        int row = wn * 64 + f * 16 + li;
        Bfr[f] = *(const bf16v8*)(sB + row * 64 + (((s * 4 + qd) ^ (row & 7)) << 3));
      }
#pragma unroll
      for (int r = 0; r < 4; ++r)
#pragma unroll
        for (int f = 0; f < 4; ++f)
          acc[r][f] = __builtin_amdgcn_mfma_f32_16x16x32_bf16(Afr[r], Bfr[f], acc[r][f], 0, 0, 0);
    }
  }
  __syncthreads();              // all LDS reads done before smem reuse

  if (m0 >= 512) {
    // ---- v rows: restage through LDS -> coalesced 16B stores to v4[ch][tok] ----
    int ch0 = m0 - 512;
#pragma unroll
    for (int r = 0; r < 4; ++r)
#pragma unroll
      for (int f = 0; f < 4; ++f) {
        int coll = wn * 64 + f * 16 + li;
#pragma unroll
        for (int rr = 0; rr < 4; ++rr) {
          int rowl = wm * 64 + r * 16 + qd * 4 + rr;
          actt[rowl * 136 + coll] =
              __float2bfloat16(acc[r][f][rr] + sf(v_b[ch0 + rowl]));
        }
      }
    __syncthreads();
#pragma unroll
    for (int it = 0; it < 8; ++it) {
      int g = it * 256 + t;
      int row = g >> 4, c16 = g & 15;
      bf16v8 vv = *(const bf16v8*)(actt + row * 136 + c16 * 8);
      *(bf16v8*)(v4 + ((size_t)b * DH + ch0 + row) * NTOK + n0b + c16 * 8) = vv;
    }
  } else {
    // ---- q/k rows: packed 8B stores (4 consecutive kd per thread) ----
    const float* bias = (m0 < 256) ? q_b : k_b;
    bf16* dst = (m0 < 256) ? qT : kT;
    int mb = (m0 < 256) ? m0 : m0 - 256;
#pragma unroll
    for (int r = 0; r < 4; ++r)
#pragma unroll
      for (int f = 0; f < 4; ++f) {
        int n = n0b + wn * 64 + f * 16 + li;
        int rowg = mb + wm * 64 + r * 16 + qd * 4;
        int h = rowg >> 5, kd = rowg & 31;
        union { bf16 e[4]; uint2 u; } pk;
#pragma unroll
        for (int rr = 0; rr < 4; ++rr)
          pk.e[rr] = __float2bfloat16(acc[r][f][rr] + sf(bias[rowg + rr]));
        *(uint2*)(dst + (((size_t)b * NH + h) * NTOK + n) * KD + kd) = pk.u;
      }
  }
}

// ---------------- K2: scores + TH1 + softmax + TH2 -> P blocked [b][g][nt16][mb8][nl16][m32] ----------------
__global__ __launch_bounds__(512, 2) void k_scores(const bf16* __restrict__ qT,
    const bf16* __restrict__ kT, const float* __restrict__ bias_full,
    const float* __restrict__ th1_w, const float* __restrict__ th1_b,
    const float* __restrict__ th2_w, const float* __restrict__ th2_b,
    bf16* __restrict__ P, int nb) {
  __shared__ bf16 stage[4][8][16][32];   // 32 KB: [g2 round][wave][nl][m]
  __shared__ float s_th1[64], s_th2[64], s_t1b[8], s_t2b[8];
  __shared__ float s_part[8][8][16];
  __shared__ float s_invl[8][16];
  int t = threadIdx.x;
  if (t < 64) { s_th1[t] = sf(th1_w[t]); s_th2[t] = sf(th2_w[t]); }
  if (t >= 64 && t < 72) s_t1b[t - 64] = sf(th1_b[t - 64]);
  if (t >= 72 && t < 80) s_t2b[t - 72] = sf(th2_b[t - 72]);
  int id = blockIdx.x;
  int b, nt;
  if ((nb & 7) == 0) {
    int per = nb >> 3;
    int xcd = id & 7, slot = id >> 3;
    b = xcd * per + (slot % per);
    nt = slot / per;            // [0,16)
  } else { b = id >> 4; nt = id & 15; }
  int n0 = nt * 16;
  int wave = t >> 6, lane = t & 63, qd = lane >> 4, li = lane & 15;
  int ms = wave * 32;

  // ---- QK^T: S[h][mt][r] at (n = n0+qd*4+r, m = ms+mt*16+li) ----
  f32x4 S[8][2];
#pragma unroll
  for (int h = 0; h < 8; ++h) {
    bf16v8 Af = *(const bf16v8*)(qT + (((size_t)b * NH + h) * NTOK + n0 + li) * KD + qd * 8);
#pragma unroll
    for (int mt = 0; mt < 2; ++mt) {
      bf16v8 Bf = *(const bf16v8*)(kT + (((size_t)b * NH + h) * NTOK + ms + mt * 16 + li) * KD + qd * 8);
      f32x4 c = {0.f, 0.f, 0.f, 0.f};
      S[h][mt] = __builtin_amdgcn_mfma_f32_16x16x32_bf16(Af, Bf, c, 0, 0, 0);
    }
  }
  // bias add: coalesced independent loads from bias_full
#pragma unroll
  for (int h = 0; h < 8; ++h)
#pragma unroll
    for (int mt = 0; mt < 2; ++mt)
#pragma unroll
      for (int r = 0; r < 4; ++r)
        S[h][mt][r] = S[h][mt][r] * SCALE +
            bias_full[(size_t)(h * NTOK + n0 + qd * 4 + r) * NTOK + ms + mt * 16 + li];
  __syncthreads();   // th weights staged

  // ---- TH1 + exp (no max-sub; clamp firewall) + row sums ----
  float psum[8][4];
#pragma unroll
  for (int g = 0; g < 8; ++g)
#pragma unroll
    for (int r = 0; r < 4; ++r) psum[g][r] = 0.f;
#pragma unroll
  for (int mt = 0; mt < 2; ++mt)
#pragma unroll
    for (int r = 0; r < 4; ++r) {
      float e[8];
#pragma unroll
      for (int g = 0; g < 8; ++g) {
        float a = s_t1b[g];
#pragma unroll
        for (int h = 0; h < 8; ++h) a += s_th1[g * 8 + h] * S[h][mt][r];
        e[g] = __expf(fminf(a, 30.0f));
        psum[g][r] += e[g];
      }
#pragma unroll
      for (int g = 0; g < 8; ++g) S[g][mt][r] = e[g];
    }
#pragma unroll
  for (int g = 0; g < 8; ++g)
#pragma unroll
    for (int r = 0; r < 4; ++r) {
      float v = psum[g][r];
      v += __shfl_xor(v, 1, 64);
      v += __shfl_xor(v, 2, 64);
      v += __shfl_xor(v, 4, 64);
      v += __shfl_xor(v, 8, 64);
      psum[g][r] = v;
    }
  if (li == 0) {
#pragma unroll
    for (int g = 0; g < 8; ++g)
#pragma unroll
      for (int r = 0; r < 4; ++r) s_part[wave][g][qd * 4 + r] = psum[g][r];
  }
  __syncthreads();
  if (t < 128) {
    int g = t >> 4, n = t & 15;
    float ssum = 0.f;
#pragma unroll
    for (int w2 = 0; w2 < 8; ++w2) ssum += s_part[w2][g][n];
    s_invl[g][n] = 1.0f / ssum;
  }
  __syncthreads();
#pragma unroll
  for (int g = 0; g < 8; ++g)
#pragma unroll
    for (int mt = 0; mt < 2; ++mt)
#pragma unroll
      for (int r = 0; r < 4; ++r)
        S[g][mt][r] *= s_invl[g][qd * 4 + r];

  // ---- TH2 + blocked-coalesced P store via LDS restage (2 rounds of 4 g2) ----
  size_t pb = (size_t)b * NH * 65536 + (size_t)nt * 4096 + wave * 512 + lane * 8;
#pragma unroll
  for (int gr = 0; gr < 2; ++gr) {
#pragma unroll
    for (int g2i = 0; g2i < 4; ++g2i) {
      int g2 = gr * 4 + g2i;
#pragma unroll
      for (int mt = 0; mt < 2; ++mt)
#pragma unroll
        for (int r = 0; r < 4; ++r) {
          float a = s_t2b[g2];
#pragma unroll
          for (int g = 0; g < 8; ++g) a += s_th2[g2 * 8 + g] * S[g][mt][r];
          stage[g2i][wave][qd * 4 + r][mt * 16 + li] = __float2bfloat16(a);
        }
    }
    __syncthreads();
#pragma unroll
    for (int g2i = 0; g2i < 4; ++g2i) {
      int g2 = gr * 4 + g2i;
      bf16v8 vv = *(const bf16v8*)&stage[g2i][wave][lane >> 2][(lane & 3) * 8];
      *(bf16v8*)(P + pb + (size_t)g2 * 65536) = vv;
    }
    __syncthreads();
  }
}

// ---------------- K3: O = P@V + dwconv + relu -> act[b,n,ch] ----------------
static __device__ __forceinline__ int vswz(int ch, int tok) {
  return tok ^ ((ch & 7) << 3);
}

__global__ __launch_bounds__(512, 1) void k_pv(const bf16* __restrict__ P,
    const bf16* __restrict__ v4,
    const float* __restrict__ vl_w, const float* __restrict__ vl_b,
    bf16* __restrict__ act, int nb) {
  __shared__ bf16 v_s[128][256];     // 64 KB, bank-swizzled via vswz()
  __shared__ bf16 act_s[256][136];   // 68 KB (+8 pad)
  __shared__ float wv_s[1152];       // dw weights for this head: 4.5 KB
  __shared__ float vb_s[128];
  int id = blockIdx.x;
  int b, h;
  if ((nb & 7) == 0) {
    int per = nb >> 3;
    int xcd = id & 7, slot = id >> 3;
    b = xcd * per + (slot % per);
    h = slot / per;            // [0,8)
  } else { b = id >> 3; h = id & 7; }
  int t = threadIdx.x;
  int wave = t >> 6, lane = t & 63;
  int qd = lane >> 4, li = lane & 15;
  int nw = wave * 32;                // 32 tokens per wave
  int nwt = wave * 2;                // n-tile base
  const bf16* Pb = P + ((size_t)b * NH + h) * 65536;
  const bf16* Vb = v4 + ((size_t)b * DH + h * DHEAD) * NTOK;

  // --- prefetch ALL P fragments (latency hides under V staging; drained by barrier) ---
  bf16v8 Af[4][2][2];
#pragma unroll
  for (int mi = 0; mi < 4; ++mi)
#pragma unroll
    for (int s = 0; s < 2; ++s)
#pragma unroll
      for (int r = 0; r < 2; ++r)
        Af[mi][s][r] = *(const bf16v8*)(Pb + (size_t)(nwt + r) * 4096 +
                                        (mi * 2 + s) * 512 + li * 32 + qd * 8);

  // --- stage V slab (coalesced 16B, swizzled LDS dest) + dw weights ---
#pragma unroll
  for (int p = 0; p < 8; ++p) {
    int idx = p * 512 + t;             // 16-B granule id, 4096 total
    int ch = idx >> 5, tok = (idx & 31) * 8;
    *(bf16v8*)&v_s[ch][vswz(ch, tok)] = *(const bf16v8*)(Vb + (size_t)ch * NTOK + tok);
  }
  for (int i = t; i < 1152; i += 512) wv_s[i] = sf(vl_w[(size_t)h * DHEAD * 9 + i]);
  if (t < 128) vb_s[t] = sf(vl_b[h * DHEAD + t]);
  __syncthreads();

  // --- PV GEMM: B operand from swizzled LDS ---
  f32x4 acc[2][8];
#pragma unroll
  for (int r = 0; r < 2; ++r)
#pragma unroll
    for (int f = 0; f < 8; ++f) acc[r][f] = (f32x4){0.f, 0.f, 0.f, 0.f};
#pragma unroll
  for (int mi = 0; mi < 4; ++mi) {
    int m0 = mi * 64;
#pragma unroll
    for (int s = 0; s < 2; ++s) {
      bf16v8 Bf[8];
#pragma unroll
      for (int f = 0; f < 8; ++f) {
        int ch = f * 16 + li;
        Bf[f] = *(const bf16v8*)&v_s[ch][vswz(ch, m0 + s * 32 + qd * 8)];
      }
#pragma unroll
      for (int f = 0; f < 8; ++f)
#pragma unroll
        for (int r = 0; r < 2; ++r)
          acc[r][f] = __builtin_amdgcn_mfma_f32_16x16x32_bf16(Af[mi][s][r], Bf[f], acc[r][f], 0, 0, 0);
    }
  }

  // --- epilogue: dwconv 3x3 entirely from LDS + relu -> act_s ---
#pragma unroll
  for (int f = 0; f < 8; ++f) {
    int chl = f * 16 + li;
    float wv[9];
#pragma unroll
    for (int j = 0; j < 9; ++j) wv[j] = wv_s[chl * 9 + j];
    float vb = vb_s[chl];
#pragma unroll
    for (int r = 0; r < 2; ++r) {
      int nbase = nw + r * 16;          // y = nbase/16, x = qd*4..qd*4+3
      int y = nbase >> 4;
      float vv[3][6];
#pragma unroll
      for (int yy = 0; yy < 3; ++yy) {
        int y3 = y - 1 + yy;
#pragma unroll
        for (int c = 0; c < 6; ++c) {
          int x = qd * 4 - 1 + c;
          vv[yy][c] = (y3 >= 0 && y3 < 16 && x >= 0 && x < 16)
                      ? __bfloat162float(v_s[chl][vswz(chl, y3 * 16 + x)]) : 0.f;
        }
      }
#pragma unroll
      for (int rr = 0; rr < 4; ++rr) {
        float s = vb;
#pragma unroll
        for (int yy = 0; yy < 3; ++yy)
#pragma unroll
          for (int j = 0; j < 3; ++j)
            s += vv[yy][rr + j] * wv[yy * 3 + j];
        float v = fmaxf(acc[r][f][rr] + s, 0.f);
        act_s[nbase + qd * 4 + rr][chl] = __float2bfloat16(v);
      }
    }
  }
  __syncthreads();
  // coalesced act write: rows of 256 B (128 ch x bf16)
  for (int it = t; it < 4096; it += 512) {
    int row = it >> 4, seg = it & 15;
    bf16v8 vv = *(const bf16v8*)&act_s[row][seg * 8];
    *(bf16v8*)(act + ((size_t)b * NTOK + row) * DH + h * DHEAD + seg * 8) = vv;
  }
}

// ---------------- K4: proj GEMM out[b,dim,tok] = wp @ act^T + proj_b ----------------
__global__ __launch_bounds__(256, 4) void k_proj(const bf16* __restrict__ act,
    const bf16* __restrict__ proj_w, const float* __restrict__ proj_b,
    int b_base, int nb, float* __restrict__ out) {
  int id = blockIdx.x;
  int b, mt;
  if ((nb & 7) == 0) {
    int per = nb >> 3;
    int xcd = id & 7, slot = id >> 3;
    b = xcd * per + (slot % per);
    mt = slot / per;            // [0,6)
  } else { b = id / 6; mt = id % 6; }
  int m0 = mt * 64;
  int bg = b_base + b;
  int wave = threadIdx.x >> 6, lane = threadIdx.x & 63;
  int qd = lane >> 4, li = lane & 15;
  int n0 = wave * 64;
  f32x4 acc[4][4];
#pragma unroll
  for (int r = 0; r < 4; ++r)
#pragma unroll
    for (int f = 0; f < 4; ++f) acc[r][f] = (f32x4){0.f, 0.f, 0.f, 0.f};
  for (int k0 = 0; k0 < DH; k0 += 32) {
    bf16v8 Af[4], Bf[4];
#pragma unroll
    for (int r = 0; r < 4; ++r)
      Af[r] = *(const bf16v8*)(proj_w + (size_t)(m0 + r * 16 + li) * DH + k0 + qd * 8);
#pragma unroll
    for (int f = 0; f < 4; ++f)
      Bf[f] = *(const bf16v8*)(act + ((size_t)b * NTOK + n0 + f * 16 + li) * DH + k0 + qd * 8);
#pragma unroll
    for (int r = 0; r < 4; ++r)
#pragma unroll
      for (int f = 0; f < 4; ++f)
        acc[r][f] = __builtin_amdgcn_mfma_f32_16x16x32_bf16(Af[r], Bf[f], acc[r][f], 0, 0, 0);
  }
#pragma unroll
  for (int r = 0; r < 4; ++r)
#pragma unroll
    for (int f = 0; f < 4; ++f) {
      int n = n0 + f * 16 + li;
#pragma unroll
      for (int rr = 0; rr < 4; ++rr) {
        int dim = m0 + r * 16 + qd * 4 + rr;
        out[((size_t)bg * DIM + dim) * NTOK + n] = acc[r][f][rr] + sf(proj_b[dim]);
      }
    }
}

extern "C" void kernel_launch(void* const* d_in, const int* in_sizes, int n_in,
                              void* d_out, int out_size, void* d_ws, size_t ws_size,
                              hipStream_t stream) {
  const float* x      = (const float*)d_in[0];
  const float* q_w    = (const float*)d_in[1];
  const float* q_b    = (const float*)d_in[2];
  const float* k_w    = (const float*)d_in[3];
  const float* k_b    = (const float*)d_in[4];
  const float* v_w    = (const float*)d_in[5];
  const float* v_b    = (const float*)d_in[6];
  const float* vl_w   = (const float*)d_in[7];
  const float* vl_b   = (const float*)d_in[8];
  const float* th1_w  = (const float*)d_in[9];
  const float* th1_b  = (const float*)d_in[10];
  const float* th2_w  = (const float*)d_in[11];
  const float* th2_b  = (const float*)d_in[12];
  const float* proj_w = (const float*)d_in[13];
  const float* proj_b = (const float*)d_in[14];
  const float* attn_b = (const float*)d_in[15];
  const int*   idxs   = (const int*)d_in[16];
  int n_off = in_sizes[15] / NH;
  float* out = (float*)d_out;

  const size_t WQ = 98304, WK = 98304, WV = 393216, WP = 393216;
  const size_t WTOT = WQ + WK + WV + WP;                       // 983040 elem
  const size_t BFULL = (size_t)NH * NTOK * NTOK;               // 524288 f32
  const size_t PB_XT = (size_t)NTOK * DIM;                     // 98304
  const size_t PB_QK = (size_t)NH * NTOK * KD;                 // 65536
  const size_t PB_V  = (size_t)DH * NTOK;                      // 262144
  const size_t PB_AC = (size_t)NTOK * DH;                      // 262144
  const size_t PB_P  = (size_t)NH * NTOK * NTOK;               // 524288
  const size_t perb  = (PB_XT + 2 * PB_QK + PB_V + PB_AC + PB_P) * 2;  // 2555904 B
  const size_t fixed = WTOT * 2 + BFULL * 4;

  char* w = (char*)d_ws;
  bf16* wcvt = (bf16*)w;  w += WTOT * 2;
  bf16* wq = wcvt;
  bf16* wk = wcvt + WQ;
  bf16* wv = wcvt + WQ + WK;
  bf16* wp = wcvt + WQ + WK + WV;
  float* bias_full = (float*)w;  w += BFULL * 4;

  size_t rem = (ws_size > fixed) ? (ws_size - fixed) : 0;
  int CH = (int)(rem / perb);
  if (CH > BB) CH = BB;
  if (CH >= 8) CH &= ~7;      // multiple of 8 -> XCD swizzle active
  if (CH < 1) CH = 1;

  bf16* xT  = (bf16*)w;  w += (size_t)CH * PB_XT * 2;
  bf16* qT  = (bf16*)w;  w += (size_t)CH * PB_QK * 2;
  bf16* kT  = (bf16*)w;  w += (size_t)CH * PB_QK * 2;
  bf16* v4  = (bf16*)w;  w += (size_t)CH * PB_V * 2;
  bf16* act = (bf16*)w;  w += (size_t)CH * PB_AC * 2;
  bf16* P   = (bf16*)w;  w += (size_t)CH * PB_P * 2;

  k_convert<<<(int)(WTOT / 256), 256, 0, stream>>>(q_w, k_w, v_w, proj_w, wcvt);
  k_bias<<<(int)(BFULL / 256), 256, 0, stream>>>(attn_b, idxs, n_off, bias_full);

  for (int c0 = 0; c0 < BB; c0 += CH) {
    int cb = (BB - c0 < CH) ? (BB - c0) : CH;
    k_transpose_x<<<dim3(12, 8, cb), 256, 0, stream>>>(x + (size_t)c0 * DIM * NTOK, xT);
    k_qkv<<<cb * 24, 256, 0, stream>>>(xT, wcvt, q_b, k_b, v_b, qT, kT, v4, cb);
    k_scores<<<cb * 16, 512, 0, stream>>>(qT, kT, bias_full,
                                          th1_w, th1_b, th2_w, th2_b, P, cb);
    k_pv<<<cb * 16 / 2, 512, 0, stream>>>(P, v4, vl_w, vl_b, act, cb);
    k_proj<<<cb * 6, 256, 0, stream>>>(act, wp, proj_b, c0, cb, out);
  }
}